// Round 4
// baseline (168.656 us; speedup 1.0000x reference)
//
#include <hip/hip_runtime.h>

#define N_IN   256
#define NCEN   2048
#define NOUT   128
#define BR     32           // rows per WG
#define XP     264          // prologue-only padded X stride (shorts)
#define LOG2E  1.4426950408889634f

typedef __bf16 bf16x8 __attribute__((ext_vector_type(8)));
typedef float  f32x4  __attribute__((ext_vector_type(4)));

__device__ __forceinline__ unsigned short f2bf(float f) {
  unsigned int u = __builtin_bit_cast(unsigned int, f);
  u += 0x7FFFu + ((u >> 16) & 1u);            // round-to-nearest-even
  return (unsigned short)(u >> 16);
}

__device__ __forceinline__ bf16x8 ldfrag(const unsigned short* p) {
  return __builtin_bit_cast(bf16x8, *reinterpret_cast<const uint4*>(p));
}

// async 16B-per-lane global->LDS: lds dest is wave-uniform base + lane*16
__device__ __forceinline__ void gll16(const unsigned short* g, unsigned short* l) {
  __builtin_amdgcn_global_load_lds(
      (__attribute__((address_space(1))) void*)g,
      (__attribute__((address_space(3))) void*)l,
      16, 0, 0);
}

// stage W slice [128 outs x 32 k] chunk-major: chunk idx = (k>>3)*128 + o
__device__ __forceinline__ void stage_wl(const unsigned short* wbw, unsigned short* dst,
                                         int colbase, int wave, int lane) {
#pragma unroll
  for (int j = 0; j < 2; ++j) {
    const int idx0 = wave * 128 + j * 64;
    const int idx  = idx0 + lane;
    const int o    = idx & 127;
    const int k8   = idx >> 7;          // 0..3
    gll16(wbw + o * 2304 + colbase + k8 * 8, dst + idx0 * 8);
  }
}

// stage centers tile [32 c x 256 k] chunk-major: chunk idx = (k>>3)*32 + c
__device__ __forceinline__ void stage_cb(const unsigned short* cbw, unsigned short* dst,
                                         int centerbase, int wave, int lane) {
#pragma unroll
  for (int j = 0; j < 4; ++j) {
    const int idx0 = wave * 256 + j * 64;
    const int idx  = idx0 + lane;
    const int c    = idx & 31;
    const int kc   = idx >> 5;          // 0..31
    gll16(cbw + (centerbase + c) * 256 + kc * 8, dst + idx0 * 8);
  }
}

// ---------------- prep: fp32 -> bf16 for centers & W, plus |c|^2 ----------------
__global__ __launch_bounds__(256) void rbfn_prep(
    const float* __restrict__ centers, const float* __restrict__ W,
    unsigned short* __restrict__ cbw, unsigned short* __restrict__ wbw,
    float* __restrict__ csq)
{
  const int b = blockIdx.x;
  const int tid = threadIdx.x;
  if (b < 512) {                      // centers: 4 rows per block, 1 wave per row
    const int wave = tid >> 6, lane = tid & 63;
    const int row = b * 4 + wave;
    float4 v = reinterpret_cast<const float4*>(centers + row * N_IN)[lane];
    float ss = v.x * v.x + v.y * v.y + v.z * v.z + v.w * v.w;
    ushort4 pk = { f2bf(v.x), f2bf(v.y), f2bf(v.z), f2bf(v.w) };
    reinterpret_cast<ushort4*>(cbw + row * N_IN)[lane] = pk;
    for (int off = 32; off > 0; off >>= 1) ss += __shfl_down(ss, off, 64);
    if (lane == 0) csq[row] = ss;
  } else {                            // W: flat float4 -> bf16x4
    const int f = (b - 512) * 256 + tid;   // 73728 float4 total, exact
    float4 v = reinterpret_cast<const float4*>(W)[f];
    ushort4 pk = { f2bf(v.x), f2bf(v.y), f2bf(v.z), f2bf(v.w) };
    reinterpret_cast<ushort4*>(wbw)[f] = pk;
  }
}

// ---------------- fused main kernel ----------------
// 512 WGs x 256 thr (4 waves), 32 rows/WG. LDS ~51 KB -> 3 blocks/CU cap,
// grid gives 2 resident -> two independent barrier domains per CU (latency overlap).
// Wave split: mw = wave&1 (16-row half), nw = wave>>1 (center/out half).
__global__ __launch_bounds__(256, 3) void rbfn_main(
    const float* __restrict__ X, const float* __restrict__ beta,
    const float* __restrict__ bias,
    const unsigned short* __restrict__ cbw,   // [2048][256] bf16
    const unsigned short* __restrict__ wbw,   // [128][2304] bf16
    const float* __restrict__ csq,            // [2048]
    float* __restrict__ out)                  // [16384][128] fp32
{
  __shared__ __align__(16) unsigned char pool[52352];
  unsigned short* const CB0 = (unsigned short*)(pool);            // 16 KB
  unsigned short* const CB1 = (unsigned short*)(pool + 16384);    // 16 KB
  unsigned short* const WL0 = (unsigned short*)(pool + 32768);    //  8 KB
  unsigned short* const WL1 = (unsigned short*)(pool + 40960);    //  8 KB
  unsigned short* const RBm = (unsigned short*)(pool + 49152);    //  2 KB [32r x 32c]
  float* const xsq  = (float*)(pool + 51200);                     // 32 f
  float* const pred = (float*)(pool + 51328);                     // 256 f
  unsigned short* const Xb = (unsigned short*)pool;               // prologue alias (16.9 KB)

  const int tid  = threadIdx.x;
  const int wave = tid >> 6;
  const int lane = tid & 63;
  const int l16  = lane & 15;
  const int quad = lane >> 4;
  const int mw   = wave & 1;
  const int nw   = wave >> 1;
  const int r0   = blockIdx.x * BR;

  // --- prologue: stage X tile fp32->bf16 into Xb, |x|^2 partials ---
  {
    const int row = tid >> 3;          // 0..31
    const int q   = tid & 7;
    const float4* gx = reinterpret_cast<const float4*>(X + (r0 + row) * N_IN) + q * 8;
    float ss = 0.f;
#pragma unroll
    for (int j = 0; j < 8; ++j) {
      float4 v = gx[j];
      ss += v.x * v.x + v.y * v.y + v.z * v.z + v.w * v.w;
      ushort4 pk = { f2bf(v.x), f2bf(v.y), f2bf(v.z), f2bf(v.w) };
      *reinterpret_cast<ushort4*>(&Xb[row * XP + q * 32 + j * 4]) = pk;
    }
    pred[tid] = ss;
  }
  __syncthreads();
  if (tid < 32) {
    float s = 0.f;
#pragma unroll
    for (int k = 0; k < 8; ++k) s += pred[tid * 8 + k];
    xsq[tid] = s;
  }
  stage_wl(wbw, WL0, 0, wave, lane);   // W cols 0..31 for X-part iter 0

  // persistent A fragments: this wave's 16 rows x 256 k (32 VGPR)
  bf16x8 areg[8];
#pragma unroll
  for (int kb = 0; kb < 8; ++kb)
    areg[kb] = ldfrag(&Xb[(mw * 16 + l16) * XP + kb * 32 + quad * 8]);

  f32x4 oacc[4] = {};                  // 16 rows x 64 outs per wave

  // === X-part: 8 iters of K=32, A from registers ===
#pragma unroll
  for (int it = 0; it < 8; ++it) {
    __syncthreads();                   // drains staging issued last iter
    if (it < 7) {
      stage_wl(wbw, ((it + 1) & 1) ? WL1 : WL0, (it + 1) * 32, wave, lane);
    } else {
      stage_wl(wbw, WL0, 256, wave, lane);        // radial rb=0 W slice
      stage_cb(cbw, CB0, 0, wave, lane);          // radial rb=0 centers
    }
    const unsigned short* WLb = (it & 1) ? WL1 : WL0;
#pragma unroll
    for (int ot = 0; ot < 4; ++ot) {
      bf16x8 bfr = ldfrag(&WLb[(quad * 128 + nw * 64 + ot * 16 + l16) * 8]);
      oacc[ot] = __builtin_amdgcn_mfma_f32_16x16x32_bf16(areg[it], bfr, oacc[ot], 0, 0, 0);
    }
  }

  // === radial part: 64 center blocks of 32 ===
  for (int rb = 0; rb < 64; ++rb) {
    __syncthreads();                   // drains staging issued one iter ago
    const int buf = rb & 1;
    const unsigned short* const CBb = buf ? CB1 : CB0;
    const unsigned short* const WLb = buf ? WL1 : WL0;
    if (rb < 63) {
      stage_cb(cbw, buf ? CB0 : CB1, (rb + 1) * 32, wave, lane);
      stage_wl(wbw, buf ? WL0 : WL1, 256 + (rb + 1) * 32, wave, lane);
    }
    const int   cg     = rb * 32 + nw * 16 + l16;
    const float my_cs  = csq[cg];
    const float my_nb2 = -LOG2E * beta[cg];

    // cross GEMM: wave = 16 rows x 16 centers, K=256, A from regs
    f32x4 cacc = {};
#pragma unroll
    for (int kb = 0; kb < 8; ++kb) {
      bf16x8 bfr = ldfrag(&CBb[((kb * 4 + quad) * 32 + nw * 16 + l16) * 8]);
      cacc = __builtin_amdgcn_mfma_f32_16x16x32_bf16(areg[kb], bfr, cacc, 0, 0, 0);
    }

    // epilogue: radial = exp2(-beta*log2e * sq_dist) -> RBm (chunk-major)
    const int c_lo = nw * 16 + l16;
#pragma unroll
    for (int r = 0; r < 4; ++r) {
      const int row = mw * 16 + quad * 4 + r;     // D: row = quad*4 + reg
      float sd  = xsq[row] + my_cs - 2.f * cacc[r];
      RBm[((c_lo >> 3) * 32 + row) * 8 + (c_lo & 7)] = f2bf(exp2f(my_nb2 * sd));
    }
    // LDS-only barrier: do NOT drain vmcnt (keeps prefetch in flight)
    asm volatile("s_waitcnt lgkmcnt(0)\n\ts_barrier" ::: "memory");

    // feats GEMM: oacc += R[16r x 32c] @ W[:,block]^T  (K=32, 1 MFMA per out-tile)
    bf16x8 afr = ldfrag(&RBm[(quad * 32 + mw * 16 + l16) * 8]);
#pragma unroll
    for (int ot = 0; ot < 4; ++ot) {
      bf16x8 bfr = ldfrag(&WLb[(quad * 128 + nw * 64 + ot * 16 + l16) * 8]);
      oacc[ot] = __builtin_amdgcn_mfma_f32_16x16x32_bf16(afr, bfr, oacc[ot], 0, 0, 0);
    }
  }

  // --- final: add bias, store fp32 ---
#pragma unroll
  for (int ot = 0; ot < 4; ++ot) {
    const int o  = nw * 64 + ot * 16 + l16;
    const float bv = bias[o];
#pragma unroll
    for (int r = 0; r < 4; ++r) {
      const int row = r0 + mw * 16 + quad * 4 + r;
      out[row * NOUT + o] = oacc[ot][r] + bv;
    }
  }
}

extern "C" void kernel_launch(void* const* d_in, const int* in_sizes, int n_in,
                              void* d_out, int out_size, void* d_ws, size_t ws_size,
                              hipStream_t stream) {
  const float* X       = (const float*)d_in[0];   // [16384,256]
  const float* centers = (const float*)d_in[1];   // [2048,256]
  const float* beta    = (const float*)d_in[2];   // [1,2048]
  const float* W       = (const float*)d_in[3];   // [128,2304]
  const float* bias    = (const float*)d_in[4];   // [128]
  float* out = (float*)d_out;

  char* ws = (char*)d_ws;
  unsigned short* cbw = (unsigned short*)ws;                       // 1,048,576 B
  unsigned short* wbw = (unsigned short*)(ws + 1048576);           //   589,824 B
  float*          csq = (float*)(ws + 1048576 + 589824);           //     8,192 B

  rbfn_prep<<<800, 256, 0, stream>>>(centers, W, cbw, wbw, csq);
  rbfn_main<<<512, 256, 0, stream>>>(X, beta, bias, cbw, wbw, csq, out);
}